// Round 7
// baseline (400.033 us; speedup 1.0000x reference)
//
#include <hip/hip_runtime.h>

// out[M,N] = (int8 a[M,K] @ int8 w[K,N]) * a_scale[M] * w_scale[N]
// M = 8192, K = 4096, N = 4096. Inputs arrive as int32 containers.
//
// R5 measured: gemm 140.7 us (MfmaUtil 44.5, conflicts 0, 1 block/CU);
// total-gemm ~256 us invariant across 3 pack rewrites => mostly fixed harness
// traffic; packs left as-is. R6/R7: GEMM register read-ahead pipeline —
// fragment regs double-buffered; ds_reads for tile T+1 issued BEFORE tile T's
// MFMA cluster (pinned by sched_barrier so the compiler cannot sink them) and
// waited one iteration later, so LDS read service (~1130 cy) overlaps the
// MFMA window (~1165 cy) instead of alternating with it.

#define M_TOT 8192
#define N_TOT 4096
#define K_TOT 4096
#define NT_K  (K_TOT / 64)     // 64 K-tiles of depth 64
#define TILE_BYTES 16384       // 256 rows x 64 k x 1 B

typedef int v4i  __attribute__((ext_vector_type(4)));
typedef int v16i __attribute__((ext_vector_type(16)));

typedef const __attribute__((address_space(1))) unsigned char* gas1_t;
typedef __attribute__((address_space(3))) unsigned char* las3_t;

__device__ __forceinline__ int pack4(int4 v) {
    return (int)((unsigned)(v.x & 255) | ((unsigned)(v.y & 255) << 8) |
                 ((unsigned)(v.z & 255) << 16) | ((unsigned)v.w << 24));
}

// ---------------------------------------------------------------------------
// Pack A: a[M][K] int32 -> a8 tiles [mt(32)][kt(64)][slot(4)][m(256)][16B]
// (unchanged from R5)
// ---------------------------------------------------------------------------
__global__ __launch_bounds__(256) void pack_a_kernel(const int* __restrict__ a,
                                                     unsigned char* __restrict__ a8) {
    __shared__ int4 stage[128 * 16];        // 32 KB, addr16 = r*16 + (c ^ (r&15))
    const int b = blockIdx.x;               // m128_idx*64 + kt
    const int kt = b & (NT_K - 1);
    const int m128 = b >> 6;                // 0..63
    const int mt = m128 >> 1;
    const int mhalf = m128 & 1;
    const int t = threadIdx.x;
#pragma unroll
    for (int i = 0; i < 8; ++i) {
        const int idx16 = i * 256 + t;
        const int r = idx16 >> 4;           // row 0..127
        const int c = idx16 & 15;           // 16B chunk within row
        int4 v = *(const int4*)(a + (size_t)(mt * 256 + mhalf * 128 + r) * K_TOT +
                                kt * 64 + c * 4);
        stage[r * 16 + (c ^ (r & 15))] = v;
    }
    __syncthreads();
    unsigned char* outp = a8 + (size_t)(mt * NT_K + kt) * TILE_BYTES;
#pragma unroll
    for (int q = 0; q < 2; ++q) {
        const int id = q * 256 + t;         // 0..511
        const int j = id >> 7;              // slot 0..3
        const int r = id & 127;             // row 0..127
        int4 d0 = stage[r * 16 + ((j * 4 + 0) ^ (r & 15))];
        int4 d1 = stage[r * 16 + ((j * 4 + 1) ^ (r & 15))];
        int4 d2 = stage[r * 16 + ((j * 4 + 2) ^ (r & 15))];
        int4 d3 = stage[r * 16 + ((j * 4 + 3) ^ (r & 15))];
        int4 p = { pack4(d0), pack4(d1), pack4(d2), pack4(d3) };
        *(int4*)(outp + j * 4096 + (mhalf * 128 + r) * 16) = p;
    }
}

// ---------------------------------------------------------------------------
// Pack W (transpose): w[K][N] int32 -> w8 tiles [nt(16)][kt(64)][slot(4)][n(256)][16B]
// (unchanged from R5)
// ---------------------------------------------------------------------------
__global__ __launch_bounds__(256) void pack_w_kernel(const int* __restrict__ w,
                                                     unsigned char* __restrict__ w8) {
    __shared__ int stage[64 * 128];         // 32 KB, [k][n] dwords
    const int b = blockIdx.x;               // n128_idx*64 + kt
    const int kt = b & (NT_K - 1);
    const int n128 = b >> 6;                // 0..31
    const int nt = n128 >> 1;
    const int nhalf = n128 & 1;
    const int t = threadIdx.x;
#pragma unroll
    for (int i = 0; i < 8; ++i) {
        const int idx = i * 256 + t;        // 0..2047
        const int k = idx >> 5;             // k-row 0..63
        const int c4 = idx & 31;            // int4 chunk (32 per row)
        int4 v = *(const int4*)(w + (size_t)(kt * 64 + k) * N_TOT +
                                nt * 256 + nhalf * 128 + c4 * 4);
        *(int4*)&stage[k * 128 + c4 * 4] = v;
    }
    __syncthreads();
    unsigned char* outp = w8 + (size_t)(nt * NT_K + kt) * TILE_BYTES;
#pragma unroll
    for (int q = 0; q < 2; ++q) {
        const int id = q * 256 + t;         // 0..511
        const int j = id >> 7;              // slot 0..3
        const int n = id & 127;             // col 0..127
        int4 p;
#pragma unroll
        for (int qq = 0; qq < 4; ++qq) {
            int4 bb;
            bb.x = stage[(j * 16 + qq * 4 + 0) * 128 + n];
            bb.y = stage[(j * 16 + qq * 4 + 1) * 128 + n];
            bb.z = stage[(j * 16 + qq * 4 + 2) * 128 + n];
            bb.w = stage[(j * 16 + qq * 4 + 3) * 128 + n];
            ((int*)&p)[qq] = pack4(bb);
        }
        *(int4*)(outp + j * 4096 + (nhalf * 128 + n) * 16) = p;
    }
}

// ---------------------------------------------------------------------------
// GEMM: 256x256 tile, BK=64, 8 waves (2M x 4N; 128x64 out per wave),
// mfma_i32_32x32x32_i8, quad-buffered LDS (128 KB), prefetch distance 3,
// REGISTER READ-AHEAD: fragment regs double-buffered (sets A/B); iter T
// issues ds_reads of tile T+1 before the MFMA cluster on tile T's regs
// (sched_barrier-pinned), waits them at iter T+1's lgkmcnt(0). vmcnt never 0
// in-loop.
//
// Per-iter hazards: vmcnt(8)+barrier => tile T+1 landed for all waves before
// its reads; lgkmcnt(0) before MFMA + end-barrier => all waves' reads of
// tile T complete before iter T+1's stage overwrites buf[T%4].
//
// A-frag: lane l holds A[row = l&31][k = kc*32 + (l>>5)*16 + j], j=0..15
// B-frag: lane l holds B[k][col = l&31] (consistent k-permutation cancels)
// D: lane l, reg r -> row = (r&3) + 8*(r>>2) + 4*(l>>5), col = l&31
// ---------------------------------------------------------------------------
__global__ __launch_bounds__(512, 2) void gemm_i8_kernel(
    const unsigned char* __restrict__ a8, const unsigned char* __restrict__ w8,
    const float* __restrict__ a_scale, const float* __restrict__ w_scale,
    float* __restrict__ out) {

    __shared__ __attribute__((aligned(16))) unsigned char sm[4][2][TILE_BYTES]; // 128 KB

    const int t = threadIdx.x;
    const int lane = t & 63;
    const int wid = t >> 6;           // 0..7
    const int wr = wid >> 2;          // 0..1 : rows [wr*128, +128)
    const int wc = wid & 3;           // 0..3 : cols [wc*64, +64)
    const int hi = lane >> 5;         // k-half within 32-k chunk
    const int lo32 = lane & 31;

    // XCD-aware swizzle: grid 512, 512 % 8 == 0 -> bijective chunked map
    int bid = blockIdx.x;
    bid = (bid & 7) * (512 / 8) + (bid >> 3);
    const int mt = bid >> 4;          // 0..31
    const int nt = bid & 15;          // 0..15

    const unsigned char* a_tiles = a8 + (size_t)mt * NT_K * TILE_BYTES;
    const unsigned char* w_tiles = w8 + (size_t)nt * NT_K * TILE_BYTES;

    v16i acc[4][2] = {};

    // Fragment register double-buffer (sets A and B), kc0/kc1 each.
    v4i afA0[4], afA1[4], bfA0[2], bfA1[2];
    v4i afB0[4], afB1[4], bfB0[2], bfB1[2];

#define STAGE_TILE(bN, gaP, gbP) do {                                             \
    __builtin_amdgcn_global_load_lds((gas1_t)((gaP) + t * 16),                    \
        (las3_t)&sm[bN][0][t * 16], 16, 0, 0);                                    \
    __builtin_amdgcn_global_load_lds((gas1_t)((gaP) + 8192 + t * 16),             \
        (las3_t)&sm[bN][0][8192 + t * 16], 16, 0, 0);                             \
    __builtin_amdgcn_global_load_lds((gas1_t)((gbP) + t * 16),                    \
        (las3_t)&sm[bN][1][t * 16], 16, 0, 0);                                    \
    __builtin_amdgcn_global_load_lds((gas1_t)((gbP) + 8192 + t * 16),             \
        (las3_t)&sm[bN][1][8192 + t * 16], 16, 0, 0);                             \
} while (0)

// Issue 12 ds_read_b128 of tile in buf bN into register set P (no wait).
// slot offset: (kc*2+hi)*4096; row*16 within slot; mi/ni steps = 32*16 = 512.
#define READ_FRAGS(P, bN) do {                                                    \
    const unsigned char* lA_ = &sm[bN][0][hi * 4096 + (wr * 128 + lo32) * 16];    \
    const unsigned char* lB_ = &sm[bN][1][hi * 4096 + (wc * 64 + lo32) * 16];     \
    _Pragma("unroll")                                                             \
    for (int mi = 0; mi < 4; ++mi) af##P##0[mi] = *(const v4i*)(lA_ + mi * 512);  \
    _Pragma("unroll")                                                             \
    for (int mi = 0; mi < 4; ++mi) af##P##1[mi] = *(const v4i*)(lA_ + 8192 + mi * 512);\
    _Pragma("unroll")                                                             \
    for (int ni = 0; ni < 2; ++ni) bf##P##0[ni] = *(const v4i*)(lB_ + ni * 512);  \
    _Pragma("unroll")                                                             \
    for (int ni = 0; ni < 2; ++ni) bf##P##1[ni] = *(const v4i*)(lB_ + 8192 + ni * 512);\
} while (0)

#define MFMA_ALL(P) do {                                                          \
    _Pragma("unroll")                                                             \
    for (int mi = 0; mi < 4; ++mi)                                                \
        _Pragma("unroll")                                                         \
        for (int ni = 0; ni < 2; ++ni)                                            \
            acc[mi][ni] = __builtin_amdgcn_mfma_i32_32x32x32_i8(                  \
                af##P##0[mi], bf##P##0[ni], acc[mi][ni], 0, 0, 0);                \
    _Pragma("unroll")                                                             \
    for (int mi = 0; mi < 4; ++mi)                                                \
        _Pragma("unroll")                                                         \
        for (int ni = 0; ni < 2; ++ni)                                            \
            acc[mi][ni] = __builtin_amdgcn_mfma_i32_32x32x32_i8(                  \
                af##P##1[mi], bf##P##1[ni], acc[mi][ni], 0, 0, 0);                \
} while (0)

// Iter T: regs set CUR hold tile T (reads issued last iter). Stage T+3,
// ensure T+1 landed, wait CUR, issue reads of T+1 into NXT (pinned BEFORE the
// MFMA cluster by a sched_barrier fence), MFMA on CUR.
#define ITER(Tcur, CUR, NXT, b1, b3) do {                                         \
    const int Tp = ((Tcur) + 3 <= NT_K - 1) ? (Tcur) + 3 : NT_K - 1;              \
    STAGE_TILE(b3, a_tiles + (size_t)Tp * TILE_BYTES,                             \
                   w_tiles + (size_t)Tp * TILE_BYTES);                            \
    asm volatile("s_waitcnt vmcnt(8)" ::: "memory");                              \
    __builtin_amdgcn_s_barrier();                                                 \
    asm volatile("s_waitcnt lgkmcnt(0)" ::: "memory");                            \
    __builtin_amdgcn_sched_barrier(0);                                            \
    __builtin_amdgcn_s_setprio(1);                                                \
    READ_FRAGS(NXT, b1);                                                          \
    __builtin_amdgcn_sched_barrier(0); /* pin: all 12 ds_reads issue pre-MFMA */  \
    MFMA_ALL(CUR);                                                                \
    __builtin_amdgcn_s_setprio(0);                                                \
    __builtin_amdgcn_s_barrier();                                                 \
} while (0)

    // Prologue: stage tiles 0,1,2; vmcnt(8) -> tile 0 landed; read tile 0 -> set A.
    STAGE_TILE(0, a_tiles, w_tiles);
    STAGE_TILE(1, a_tiles + TILE_BYTES, w_tiles + TILE_BYTES);
    STAGE_TILE(2, a_tiles + 2 * TILE_BYTES, w_tiles + 2 * TILE_BYTES);
    asm volatile("s_waitcnt vmcnt(8)" ::: "memory");
    __builtin_amdgcn_s_barrier();
    READ_FRAGS(A, 0);

    // 64 K-tiles = 16 x (4 unrolled iters); reg-set and buffer indices fold.
    int T = 0;
#pragma unroll 1
    for (int u = 0; u < 16; ++u) {
        ITER(T,     A, B, 1, 3);
        ITER(T + 1, B, A, 2, 0);
        ITER(T + 2, A, B, 3, 1);
        ITER(T + 3, B, A, 0, 2);
        T += 4;
    }

    asm volatile("s_waitcnt vmcnt(0)" ::: "memory");  // drain before LDS reuse

#undef STAGE_TILE
#undef READ_FRAGS
#undef MFMA_ALL
#undef ITER

    // Stash scales in LDS (reuse sm), broadcast-read in epilogue.
    __syncthreads();   // also drains the trailing rf reads (full waitcnt)
    float* scA = (float*)&sm[0][0][0];      // 256 floats
    float* scW = scA + 256;                 // 256 floats
    if (t < 256) scA[t] = a_scale[mt * 256 + t];
    else         scW[t - 256] = w_scale[nt * 256 + (t - 256)];
    __syncthreads();

    // Epilogue: dequant + store f32.
    const int col0 = nt * 256 + wc * 64;
#pragma unroll
    for (int mi = 0; mi < 4; ++mi) {
#pragma unroll
        for (int r = 0; r < 16; ++r) {
            const int rloc = wr * 128 + mi * 32 + (r & 3) + 8 * (r >> 2) + 4 * hi;
            const float as = scA[rloc];
            float* orow = out + (size_t)(mt * 256 + rloc) * N_TOT + col0 + lo32;
#pragma unroll
            for (int ni = 0; ni < 2; ++ni)
                orow[ni * 32] = (float)acc[mi][ni][r] * as * scW[wc * 64 + ni * 32 + lo32];
        }
    }
}

// ---------------------------------------------------------------------------
extern "C" void kernel_launch(void* const* d_in, const int* in_sizes, int n_in,
                              void* d_out, int out_size, void* d_ws, size_t ws_size,
                              hipStream_t stream) {
    const int*   a       = (const int*)d_in[0];
    const float* a_scale = (const float*)d_in[1];
    const int*   w       = (const int*)d_in[2];
    const float* w_scale = (const float*)d_in[3];
    float*       out     = (float*)d_out;

    // Workspace: a8 (32 MB) + w8 (16 MB) = 48 MB
    unsigned char* a8 = (unsigned char*)d_ws;
    unsigned char* w8 = a8 + (size_t)M_TOT * K_TOT;

    pack_a_kernel<<<(M_TOT / 128) * NT_K, 256, 0, stream>>>(a, a8);   // 4096 blocks
    pack_w_kernel<<<(N_TOT / 128) * NT_K, 256, 0, stream>>>(w, w8);   // 2048 blocks
    gemm_i8_kernel<<<(M_TOT / 256) * (N_TOT / 256), 512, 0, stream>>>(
        a8, w8, a_scale, w_scale, out);                               // 512 blocks
}